// Round 1
// 344.423 us; speedup vs baseline: 1.6087x; 1.6087x over previous
//
#include <hip/hip_runtime.h>
#include <stdint.h>

// Problem constants (n=1, c=32, h=w=128, p=3)
#define NPT   16384         // points (h*w)
#define KE    64            // per-point record: 32 hi f16 | 32 lo f16
#define ROWB  8192          // 128 points * KE f16 per image row

typedef _Float16 f16;
typedef __attribute__((ext_vector_type(8))) _Float16 half8;
typedef __attribute__((ext_vector_type(4))) float floatx4;

#define AS1(p) ((const __attribute__((address_space(1))) uint32_t*)(p))
#define AS3(p) ((__attribute__((address_space(3))) uint32_t*)(p))

// -------- per-pixel fp32->2xf16 split + per-pixel channel norm --------------
// New layout: Aext[pt][64] = [hi(32) | lo(32)] f16 — only 32 channels/point,
// since the 3x3 patch structure is recovered by shifted-window GEMM + blur.
__global__ __launch_bounds__(256)
void extract_kernel(const float* __restrict__ src, const float* __restrict__ tgt,
                    f16* __restrict__ Aext, f16* __restrict__ Bext,
                    double* __restrict__ n2s, double* __restrict__ n2t) {
  __shared__ f16 bufA[256 * KE];   // 32 KB
  __shared__ f16 bufB[256 * KE];   // 32 KB
  const int tid = threadIdx.x;
  const int pt = blockIdx.x * 256 + tid;
  double sA = 0.0, sB = 0.0;
#pragma unroll
  for (int c = 0; c < 32; ++c) {
    float v = src[(c << 14) + pt];
    sA += (double)v * (double)v;
    f16 h = (f16)v;
    bufA[tid * KE + c] = h;
    bufA[tid * KE + 32 + c] = (f16)(v - (float)h);
    v = tgt[(c << 14) + pt];
    sB += (double)v * (double)v;
    h = (f16)v;
    bufB[tid * KE + c] = h;
    bufB[tid * KE + 32 + c] = (f16)(v - (float)h);
  }
  n2s[pt] = sA;
  n2t[pt] = sB;
  __syncthreads();
  const uint4* s4A = (const uint4*)bufA;
  const uint4* s4B = (const uint4*)bufB;
  uint4* gA = (uint4*)(Aext + (size_t)blockIdx.x * 256 * KE);
  uint4* gB = (uint4*)(Bext + (size_t)blockIdx.x * 256 * KE);
#pragma unroll
  for (int it = 0; it < 8; ++it) {
    gA[it * 256 + tid] = s4A[it * 256 + tid];
    gB[it * 256 + tid] = s4B[it * 256 + tid];
  }
}

// -------- patch norms = 9-tap clamped blur of per-pixel norms ----------------
__global__ __launch_bounds__(256)
void norm_blur_kernel(const double* __restrict__ n2s, const double* __restrict__ n2t,
                      float* __restrict__ rq, float* __restrict__ rp,
                      unsigned long long* __restrict__ best) {
  const int pt = blockIdx.x * 256 + threadIdx.x;
  const int y = pt >> 7, x = pt & 127;
  double sq = 0.0, sp_ = 0.0;
#pragma unroll
  for (int dy = -1; dy <= 1; ++dy) {
    int yy = y + dy; yy = yy < 0 ? 0 : (yy > 127 ? 127 : yy);
#pragma unroll
    for (int dx = -1; dx <= 1; ++dx) {
      int xx = x + dx; xx = xx < 0 ? 0 : (xx > 127 ? 127 : xx);
      sq  += n2s[(yy << 7) + xx];
      sp_ += n2t[(yy << 7) + xx];
    }
  }
  rq[pt] = (float)sq;
  rp[pt] = (float)sp_;
  best[pt] = 0xFFFFFFFFFFFFFFFFULL;
}

// --- MFMA GEMM (K=96: 3 dy-windows) + diagonal blur + fused argmin -----------
// Block (by=y, bx=v): acc = Σ_d S_{cy(y+d)}ᵀ T_{cy(v+d)}  (3 windows of K=32,
// hi/lo split, 48 MFMA/window/wave = 144 total vs 432 before). Then
// mul[x,u] = Σ_dx acc[cx(x+dx), cx(u+dx)] via a once-per-block LDS blur.
__global__ __launch_bounds__(256, 2)
void gemm_blur_argmin_kernel(const f16* __restrict__ A, const f16* __restrict__ B,
                             const float* __restrict__ rq,
                             unsigned long long* __restrict__ best) {
  __shared__ __align__(16) char smem[65536];
  f16* Ash = (f16*)smem;               // [128][64] staging, 16 KB
  f16* Bsh = (f16*)(smem + 16384);     // [128][64] staging, 16 KB
  float* Cf = (float*)smem;            // [128][128] f32 spill (epilogue), 64 KB

  // ---- supertile swizzle (unchanged): L -> (bx, by) ----
  const int L  = blockIdx.x;
  const int st = L >> 7;
  const int r  = L & 127;
  const int bx = ((st & 15) << 3) | (r & 7);
  const int by = ((st >> 4) << 4) | (r >> 3);
  const int yq = by;                   // source image row (M dim)
  const int vt = bx;                   // target image row (N dim)

  const f16* Aw[3] = { A + (size_t)(yq > 0 ? yq - 1 : 0) * ROWB,
                       A + (size_t)yq * ROWB,
                       A + (size_t)(yq < 127 ? yq + 1 : 127) * ROWB };
  const f16* Bw[3] = { B + (size_t)(vt > 0 ? vt - 1 : 0) * ROWB,
                       B + (size_t)vt * ROWB,
                       B + (size_t)(vt < 127 ? vt + 1 : 127) * ROWB };

  const int t = threadIdx.x;
  const int w = t >> 6;
  const int l = t & 63;

  // ---- staging decode: 64 lanes cover 8 rows x 8 XOR-swizzled 16B slots ----
  const int lr = l >> 3;
  const int lt = l & 7;
  const int sl = lt ^ (lr & 7);        // logical slice (linear in new layout)
  int rowOff[4];
#pragma unroll
  for (int ig = 0; ig < 4; ++ig)
    rowOff[ig] = (w * 32 + ig * 8 + lr) * KE + sl * 8;

  // ---- fragment decode (16x16x32) ----
  const int m16 = l & 15;
  const int q   = l >> 4;
  const int pHi = q ^ (m16 & 7);
  const int pLo = pHi ^ 4;
  const int wRow = (w & 1) * 64;
  const int wCol = (w >> 1) * 64;
  const int aHiOff = m16 * 64 + pHi * 8;
  const int aLoOff = m16 * 64 + pLo * 8;

  floatx4 acc[4][4] = {};

#pragma unroll
  for (int kw = 0; kw < 3; ++kw) {
    __syncthreads();
#pragma unroll
    for (int ig = 0; ig < 4; ++ig)
      __builtin_amdgcn_global_load_lds(AS1(Aw[kw] + rowOff[ig]),
                                       AS3(&Ash[(w * 32 + ig * 8) * 64]), 16, 0, 0);
#pragma unroll
    for (int ig = 0; ig < 4; ++ig)
      __builtin_amdgcn_global_load_lds(AS1(Bw[kw] + rowOff[ig]),
                                       AS3(&Bsh[(w * 32 + ig * 8) * 64]), 16, 0, 0);
    __syncthreads();

    half8 ah[4], al[4];
#pragma unroll
    for (int i = 0; i < 4; ++i) {
      ah[i] = *(const half8*)&Ash[(wRow + i * 16) * 64 + aHiOff];
      al[i] = *(const half8*)&Ash[(wRow + i * 16) * 64 + aLoOff];
    }
#pragma unroll
    for (int j = 0; j < 4; ++j) {
      half8 bh = *(const half8*)&Bsh[(wCol + j * 16) * 64 + aHiOff];
#pragma unroll
      for (int i = 0; i < 4; ++i)
        acc[i][j] = __builtin_amdgcn_mfma_f32_16x16x32_f16(ah[i], bh, acc[i][j], 0, 0, 0);
#pragma unroll
      for (int i = 0; i < 4; ++i)
        acc[i][j] = __builtin_amdgcn_mfma_f32_16x16x32_f16(al[i], bh, acc[i][j], 0, 0, 0);
    }
#pragma unroll
    for (int j = 0; j < 4; ++j) {
      half8 bl = *(const half8*)&Bsh[(wCol + j * 16) * 64 + aLoOff];
#pragma unroll
      for (int i = 0; i < 4; ++i)
        acc[i][j] = __builtin_amdgcn_mfma_f32_16x16x32_f16(ah[i], bl, acc[i][j], 0, 0, 0);
    }
  }

  // ---- spill acc to LDS, group-swizzled rows to break D=128 bank aliasing --
  // phys f32 index: row*128 + ((g ^ (row&7))<<2 | (col&3)), g = col>>2.
  __syncthreads();                     // all staging-buffer readers done
#pragma unroll
  for (int i = 0; i < 4; ++i) {
#pragma unroll
    for (int j = 0; j < 4; ++j) {
      const int col = wCol + j * 16 + m16;
      const int gc = col >> 2, cl = col & 3;
#pragma unroll
      for (int r2 = 0; r2 < 4; ++r2) {
        const int rr = wRow + i * 16 + q * 4 + r2;
        Cf[(rr << 7) + (((gc ^ (rr & 7)) << 2) | cl)] = acc[i][j][r2];
      }
    }
  }
  __syncthreads();

  // ---- diagonal 3-tap clamped blur + distance + argmin over u ----
  // out[x,u] = Cf[cx(x-1)][cx(u-1)] + Cf[x][u] + Cf[cx(x+1)][cx(u+1)]
  const int xr = t >> 1;               // output row x
  const int uh = t & 1;                // u half (64 cols each)
  const int g0 = uh << 4;              // first float4 group (of 16)
  const int xm = xr > 0 ? xr - 1 : 0;
  const int xp = xr < 127 ? xr + 1 : 127;

  const floatx4* rq4 = (const floatx4*)(rq + (vt << 7));

#define LDCF(x, g) (*(const floatx4*)&Cf[((x) << 7) + ((((g) ^ ((x) & 7))) << 2)])

  unsigned long long pk = 0xFFFFFFFFFFFFFFFFULL;
  float am_last = (uh == 0) ? LDCF(xm, 0)[0] : LDCF(xm, 15)[3];  // cx(u-1) clamp/carry
  floatx4 Ap = LDCF(xp, g0);
#pragma unroll
  for (int k = 0; k < 16; ++k) {
    const int g = g0 + k;
    const floatx4 Am = LDCF(xm, g);
    const floatx4 Ac = LDCF(xr, g);
    floatx4 ApN = Ap;
    float ap4;
    if (g < 31) { ApN = LDCF(xp, g + 1); ap4 = ApN[0]; }
    else        { ap4 = Ap[3]; }       // u=127: cx(u+1)=127
    const floatx4 rv = rq4[g];
    float o[4];
    o[0] = am_last + Ac[0] + Ap[1];
    o[1] = Am[0]   + Ac[1] + Ap[2];
    o[2] = Am[1]   + Ac[2] + Ap[3];
    o[3] = Am[2]   + Ac[3] + ap4;
    am_last = Am[3];
    Ap = ApN;
    const int colb = (vt << 7) + (g << 2);
#pragma unroll
    for (int e = 0; e < 4; ++e) {
      float f = fmaf(-2.0f, o[e], rv[e]);
      unsigned int bits = __float_as_uint(f);
      unsigned int key = (bits & 0x80000000u) ? ~bits : (bits | 0x80000000u);
      unsigned long long cand =
          ((unsigned long long)key << 32) | (unsigned)(colb + e);
      pk = pk < cand ? pk : cand;
    }
  }
  unsigned long long ov = __shfl_xor(pk, 1);
  pk = pk < ov ? pk : ov;
  if (uh == 0) atomicMin(best + (yq << 7) + xr, pk);
}

// ---------------------------- finalize ---------------------------------------
__global__ void finalize_kernel(const unsigned long long* __restrict__ best,
                                const float* __restrict__ rp,
                                float* __restrict__ out) {
  int i = blockIdx.x * 256 + threadIdx.x;
  if (i >= NPT) return;
  unsigned long long v = best[i];
  unsigned int col = (unsigned int)(v & 0xFFFFFFFFu);
  unsigned int key = (unsigned int)(v >> 32);
  unsigned int bits = (key & 0x80000000u) ? (key & 0x7FFFFFFFu) : ~key;
  float fmin = __uint_as_float(bits);
  out[i]           = (float)(col >> 7);   // idy
  out[NPT + i]     = (float)(col & 127);  // idx
  out[2 * NPT + i] = rp[i] + fmin;        // nnd
}

extern "C" void kernel_launch(void* const* d_in, const int* in_sizes, int n_in,
                              void* d_out, int out_size, void* d_ws, size_t ws_size,
                              hipStream_t stream) {
  const float* src = (const float*)d_in[0];  // source_map (1,32,128,128)
  const float* tgt = (const float*)d_in[1];  // target_map (1,32,128,128)
  float* out = (float*)d_out;

  // workspace layout (bytes):
  //   Aext: [0, 2097152)        16384 x 64 f16 [hi32|lo32]
  //   Bext: [2097152, 4194304)
  //   n2s : [4194304, 4325376)  16384 f64 per-pixel channel norms (src)
  //   n2t : [4325376, 4456448)
  //   rq  : [4456448, 4521984)  16384 fp32 patch norms (src)
  //   rp  : [4521984, 4587520)
  //   best: [4587520, 4718592)  16384 u64 packed (key<<32)|col
  char* ws = (char*)d_ws;
  f16* Aext = (f16*)(ws);
  f16* Bext = (f16*)(ws + 2097152);
  double* n2s = (double*)(ws + 4194304);
  double* n2t = (double*)(ws + 4325376);
  float* rq = (float*)(ws + 4456448);
  float* rp = (float*)(ws + 4521984);
  unsigned long long* best = (unsigned long long*)(ws + 4587520);

  extract_kernel<<<64, 256, 0, stream>>>(src, tgt, Aext, Bext, n2s, n2t);
  norm_blur_kernel<<<64, 256, 0, stream>>>(n2s, n2t, rq, rp, best);
  gemm_blur_argmin_kernel<<<16384, 256, 0, stream>>>(Aext, Bext, rq, best);
  finalize_kernel<<<NPT / 256, 256, 0, stream>>>(best, rp, out);
}